// Round 1
// baseline (331.670 us; speedup 1.0000x reference)
//
#include <hip/hip_runtime.h>
#include <math.h>

#define BATCH    16384
#define MAZE_LEN 3844
#define NIDX     120   // 2 + 62 + 56 indices used per row

// Build the used-column index table at compile time, sorted ascending so that
// adjacent lanes of a wave read adjacent columns (cache-line merging within
// one global_load instruction). Mirrors the Python _chain_indices() + IDX_A/B.
struct IdxTable { int v[128]; };

static constexpr IdxTable make_idx() {
    IdxTable a{};
    int n = 0;
    a.v[n++] = 4 * 1 + 124 * 0 + 2;      // IDX_A = 6
    a.v[n++] = 4 * 29 + 124 * 30 + 3;    // IDX_B = 3839
    for (int i = 0; i < 31; ++i) { a.v[n++] = 124 * i + 1; a.v[n++] = 124 * i + 121; }
    for (int i = 0; i < 28; ++i) { a.v[n++] = 4 * (i + 2) + 1; a.v[n++] = 4 * i + 3721; }
    // insertion sort (compile-time)
    for (int i = 1; i < NIDX; ++i) {
        int key = a.v[i]; int j = i - 1;
        while (j >= 0 && a.v[j] > key) { a.v[j + 1] = a.v[j]; --j; }
        a.v[j + 1] = key;
    }
    for (int i = NIDX; i < 128; ++i) a.v[i] = 0;  // pad: safe column 0
    return a;
}

__constant__ IdxTable c_idx = make_idx();

// One wave (64 lanes) per row. and_f with p=0 is additive under u(x)=1/x-1:
//   result = 1 / (1 + sum_i (1/x_i - 1));  -log(clamp(result, e^-90))
//          = min(log1p(S), 90)
__global__ __launch_bounds__(256) void fuzzy_chain_kernel(
        const float* __restrict__ maze, float* __restrict__ out) {
    const int lane = threadIdx.x & 63;
    const int wave = threadIdx.x >> 6;          // 4 waves/block = 4 rows/block
    const int row  = (blockIdx.x << 2) | wave;

    const float* rp = maze + (size_t)row * MAZE_LEN;

    const int c0 = c_idx.v[lane];
    const int c1 = c_idx.v[64 + lane];          // lanes >= 56 read pad (col 0), masked below

    // Issue both gathers up front (independent, latency-overlapped).
    const float x0 = rp[c0];
    const float x1 = rp[c1];

    float t = 1.0f / x0 - 1.0f;
    const float t1 = 1.0f / x1 - 1.0f;
    if (lane < NIDX - 64) t += t1;              // lanes 0..55 carry a second column

    // Full-wave butterfly reduction (64 lanes).
    #pragma unroll
    for (int off = 32; off > 0; off >>= 1)
        t += __shfl_xor(t, off, 64);

    __shared__ float s_part[4];
    if (lane == 0)
        s_part[wave] = fminf(log1pf(t), 90.0f); // clamp at exp(-90); inf -> 90 matches ref
    __syncthreads();

    if (threadIdx.x == 0) {
        const float bs = (s_part[0] + s_part[1] + s_part[2] + s_part[3])
                         * (1.0f / (float)BATCH);
        atomicAdd(out, bs);                     // device-scope by default (cross-XCD safe)
    }
}

extern "C" void kernel_launch(void* const* d_in, const int* in_sizes, int n_in,
                              void* d_out, int out_size, void* d_ws, size_t ws_size,
                              hipStream_t stream) {
    const float* maze = (const float*)d_in[0];
    float* out = (float*)d_out;

    // d_out is re-poisoned to 0xAA before every timed launch; we accumulate into it.
    hipMemsetAsync(out, 0, sizeof(float), stream);

    fuzzy_chain_kernel<<<dim3(BATCH / 4), dim3(256), 0, stream>>>(maze, out);
}

// Round 2
// 299.012 us; speedup vs baseline: 1.1092x; 1.1092x over previous
//
#include <hip/hip_runtime.h>
#include <math.h>

#define BATCH    16384
#define MAZE_LEN 3844
#define NIDX     120    // 2 + 62 + 56 used columns per row
#define NBLOCKS  (BATCH / 4)   // 4 rows per block (4 waves), 4096 blocks

// Used-column table, compile-time sorted ascending so adjacent lanes read
// adjacent/shared cache lines within one gather instruction.
struct IdxTable { int v[128]; };

static constexpr IdxTable make_idx() {
    IdxTable a{};
    int n = 0;
    a.v[n++] = 4 * 1 + 124 * 0 + 2;      // IDX_A = 6
    a.v[n++] = 4 * 29 + 124 * 30 + 3;    // IDX_B = 3839
    for (int i = 0; i < 31; ++i) { a.v[n++] = 124 * i + 1; a.v[n++] = 124 * i + 121; }
    for (int i = 0; i < 28; ++i) { a.v[n++] = 4 * (i + 2) + 1; a.v[n++] = 4 * i + 3721; }
    for (int i = 1; i < NIDX; ++i) {     // insertion sort (constexpr)
        int key = a.v[i]; int j = i - 1;
        while (j >= 0 && a.v[j] > key) { a.v[j + 1] = a.v[j]; --j; }
        a.v[j + 1] = key;
    }
    for (int i = NIDX; i < 128; ++i) a.v[i] = 0;   // pad: harmless col 0
    return a;
}

__constant__ IdxTable c_idx = make_idx();

// Math: with p=0, and_f is additive under u(x)=1/x-1, so per row
//   S = sum_i (1/x_i - 1);  -log(clamp(1/(1+S), e^-90)) = min(log1p(S), 90)
// Stage 1: one wave per row; per-block partial (sum of 4 rows) -> plain store
// into d_ws. NO atomics: 4096 same-address device-scope atomicAdds were the
// R1 bottleneck hypothesis (~80 us of serialized cross-XCD RMWs).
__global__ __launch_bounds__(256) void fuzzy_rows(
        const float* __restrict__ maze, float* __restrict__ partial) {
    const int lane = threadIdx.x & 63;
    const int wave = threadIdx.x >> 6;
    const int row  = (blockIdx.x << 2) | wave;

    const float* rp = maze + (size_t)row * MAZE_LEN;

    const int c0 = c_idx.v[lane];
    const int c1 = c_idx.v[64 + lane];

    const float x0 = rp[c0];
    const float x1 = rp[c1];

    float t = 1.0f / x0 - 1.0f;
    const float t1 = 1.0f / x1 - 1.0f;
    if (lane < NIDX - 64) t += t1;      // lanes 0..55 carry the 2nd column

    #pragma unroll
    for (int off = 32; off > 0; off >>= 1)
        t += __shfl_xor(t, off, 64);

    __shared__ float s_part[4];
    if (lane == 0)
        s_part[wave] = fminf(log1pf(t), 90.0f);  // inf -> 90 matches ref clamp
    __syncthreads();

    if (threadIdx.x == 0)
        partial[blockIdx.x] = s_part[0] + s_part[1] + s_part[2] + s_part[3];
}

// Stage 2: single block folds the 4096 partials and writes the mean.
__global__ __launch_bounds__(256) void reduce_partials(
        const float* __restrict__ partial, float* __restrict__ out) {
    float t = 0.0f;
    #pragma unroll
    for (int i = 0; i < NBLOCKS / 256; ++i)
        t += partial[threadIdx.x + (i << 8)];   // coalesced

    #pragma unroll
    for (int off = 32; off > 0; off >>= 1)
        t += __shfl_xor(t, off, 64);

    __shared__ float s_part[4];
    if ((threadIdx.x & 63) == 0)
        s_part[threadIdx.x >> 6] = t;
    __syncthreads();

    if (threadIdx.x == 0)
        out[0] = (s_part[0] + s_part[1] + s_part[2] + s_part[3])
                 * (1.0f / (float)BATCH);
}

extern "C" void kernel_launch(void* const* d_in, const int* in_sizes, int n_in,
                              void* d_out, int out_size, void* d_ws, size_t ws_size,
                              hipStream_t stream) {
    const float* maze = (const float*)d_in[0];
    float* out  = (float*)d_out;
    float* part = (float*)d_ws;   // 4096 floats; fully overwritten by K1 each call

    fuzzy_rows<<<dim3(NBLOCKS), dim3(256), 0, stream>>>(maze, part);
    reduce_partials<<<dim3(1), dim3(256), 0, stream>>>(part, out);
}

// Round 4
// 297.717 us; speedup vs baseline: 1.1140x; 1.0043x over previous
//
#include <hip/hip_runtime.h>
#include <math.h>

#define BATCH    16384
#define MAZE_LEN 3844
#define NIDX     120    // 2 + 62 + 56 used columns per row
#define NBLOCKS  (BATCH / 4)   // 4 rows per block (4 waves), 4096 blocks

// Used-column table, compile-time sorted ascending so adjacent lanes read
// adjacent/shared cache lines within one gather instruction.
struct IdxTable { int v[128]; };

static constexpr IdxTable make_idx() {
    IdxTable a{};
    int n = 0;
    a.v[n++] = 4 * 1 + 124 * 0 + 2;      // IDX_A = 6
    a.v[n++] = 4 * 29 + 124 * 30 + 3;    // IDX_B = 3839
    for (int i = 0; i < 31; ++i) { a.v[n++] = 124 * i + 1; a.v[n++] = 124 * i + 121; }
    for (int i = 0; i < 28; ++i) { a.v[n++] = 4 * (i + 2) + 1; a.v[n++] = 4 * i + 3721; }
    for (int i = 1; i < NIDX; ++i) {     // insertion sort (constexpr)
        int key = a.v[i]; int j = i - 1;
        while (j >= 0 && a.v[j] > key) { a.v[j + 1] = a.v[j]; --j; }
        a.v[j + 1] = key;
    }
    for (int i = NIDX; i < 128; ++i) a.v[i] = 0;   // pad: harmless col 0
    return a;
}

__constant__ IdxTable c_idx = make_idx();

// Math: with p=0, and_f is additive under u(x)=1/x-1, so per row
//   S = sum_i (1/x_i - 1);  -log(clamp(1/(1+S), e^-90)) = min(log1p(S), 90)
// Stage 1: one wave per row; per-block partial (sum of 4 rows) -> plain store
// into d_ws. No atomics (R1->R2: -32.7 us from removing 4096 same-address
// device-scope atomicAdds).
// NOTE: R3's 1024-thread-block + float4-stage-2 variant broke post-timing
// validation (consistent +10.84 divergence after the timed phase) for ~1.7 us
// of gain — keep this proven 256-thread structure.
__global__ __launch_bounds__(256) void fuzzy_rows(
        const float* __restrict__ maze, float* __restrict__ partial) {
    const int lane = threadIdx.x & 63;
    const int wave = threadIdx.x >> 6;
    const int row  = (blockIdx.x << 2) | wave;

    const float* rp = maze + (size_t)row * MAZE_LEN;

    const int c0 = c_idx.v[lane];
    const int c1 = c_idx.v[64 + lane];

    const float x0 = rp[c0];
    const float x1 = rp[c1];

    float t = 1.0f / x0 - 1.0f;
    const float t1 = 1.0f / x1 - 1.0f;
    if (lane < NIDX - 64) t += t1;      // lanes 0..55 carry the 2nd column

    #pragma unroll
    for (int off = 32; off > 0; off >>= 1)
        t += __shfl_xor(t, off, 64);

    __shared__ float s_part[4];
    if (lane == 0)
        s_part[wave] = fminf(log1pf(t), 90.0f);  // inf -> 90 matches ref clamp
    __syncthreads();

    if (threadIdx.x == 0)
        partial[blockIdx.x] = s_part[0] + s_part[1] + s_part[2] + s_part[3];
}

// Stage 2: single block folds the 4096 partials and writes the mean.
__global__ __launch_bounds__(256) void reduce_partials(
        const float* __restrict__ partial, float* __restrict__ out) {
    float t = 0.0f;
    #pragma unroll
    for (int i = 0; i < NBLOCKS / 256; ++i)
        t += partial[threadIdx.x + (i << 8)];   // coalesced

    #pragma unroll
    for (int off = 32; off > 0; off >>= 1)
        t += __shfl_xor(t, off, 64);

    __shared__ float s_part[4];
    if ((threadIdx.x & 63) == 0)
        s_part[threadIdx.x >> 6] = t;
    __syncthreads();

    if (threadIdx.x == 0)
        out[0] = (s_part[0] + s_part[1] + s_part[2] + s_part[3])
                 * (1.0f / (float)BATCH);
}

extern "C" void kernel_launch(void* const* d_in, const int* in_sizes, int n_in,
                              void* d_out, int out_size, void* d_ws, size_t ws_size,
                              hipStream_t stream) {
    const float* maze = (const float*)d_in[0];
    float* out  = (float*)d_out;
    float* part = (float*)d_ws;   // 4096 floats; fully overwritten by K1 each call

    fuzzy_rows<<<dim3(NBLOCKS), dim3(256), 0, stream>>>(maze, part);
    reduce_partials<<<dim3(1), dim3(256), 0, stream>>>(part, out);
}